// Round 1
// 1681.695 us; speedup vs baseline: 1.1700x; 1.1700x over previous
//
#include <hip/hip_runtime.h>
#include <math.h>

// Problem constants (fixed by setup_inputs)
constexpr int B_   = 8;
constexpr int CIN  = 64;     // dim
constexpr int C3   = 192;    // 3*dim
constexpr int HWID = 256;
constexpr long long NPIX = 65536; // 256*256

// Per-batch workspace layout (floats) — total ~21M floats (~84 MB), unchanged
constexpr size_t SZ_QKV1B = (size_t)C3 * NPIX;         // [192][65536] 1x1 out, one batch
constexpr size_t SZ_QKB   = (size_t)128 * NPIX;        // [128][65536] dw q,k one batch
constexpr size_t OFF_QKV1B = 0;
constexpr size_t OFF_QKB   = OFF_QKV1B + SZ_QKV1B;
constexpr size_t OFF_GRAM  = OFF_QKB + SZ_QKB;         // [8][2][32][32]
constexpr size_t SZ_GRAM   = (size_t)B_ * 2 * 32 * 32;
constexpr size_t OFF_NORM  = OFF_GRAM + SZ_GRAM;       // [8][2][64]
constexpr size_t SZ_NORM   = (size_t)B_ * 2 * 64;
constexpr size_t OFF_M     = OFF_NORM + SZ_NORM;       // [8][64][64]
constexpr size_t SZ_M      = (size_t)B_ * 64 * 64;

// LDS tile stride: 68 floats = 272 B, keeps row starts 16B-aligned for
// ds_read_b128 while breaking the 64-float power-of-2 bank pattern.
constexpr int LSTR = 68;

// ---------------------------------------------------------------------------
// K1: qkv1 = W_qkv (192x64) @ x_b (64xN), one batch.  LDS-tiled GEMM:
// block = 64 oc x 64 pixels, thread = 4x4 register tile.  Weights read from
// LDS (staged once/block) instead of per-lane global loads.
// grid (NPIX/64 = 1024, 3 oc-tiles).
// ---------------------------------------------------------------------------
__global__ __launch_bounds__(256) void k1_qkv1x1(const float* __restrict__ x,
                                                 const float* __restrict__ wqkv,
                                                 float* __restrict__ qkv1, int b) {
  __shared__ __align__(16) float xs[64][LSTR];   // [ic][pix]
  __shared__ __align__(16) float Wt[64][LSTR];   // [ic][oc]  (transposed W)
  const int t = threadIdx.x;
  const long long n0 = (long long)blockIdx.x * 64;
  const int oc0 = blockIdx.y * 64;
  const float* xb = x + (size_t)b * CIN * NPIX;

  // stage x tile: 16-lane groups read 256B rows (coalesced float4)
  {
    const int p4 = (t & 15) * 4;
#pragma unroll
    for (int r = 0; r < 4; ++r) {
      const int ic = (t >> 4) + 16 * r;
      const float4 v = *(const float4*)(xb + (size_t)ic * NPIX + n0 + p4);
      *(float4*)(&xs[ic][p4]) = v;
    }
    // stage W^T: read W[oc][ic] rows coalesced, scatter into Wt[ic][oc]
    const int ic4 = (t & 15) * 4;
#pragma unroll
    for (int r = 0; r < 4; ++r) {
      const int ocl = (t >> 4) + 16 * r;
      const float4 w = *(const float4*)(wqkv + (size_t)(oc0 + ocl) * 64 + ic4);
      Wt[ic4 + 0][ocl] = w.x;
      Wt[ic4 + 1][ocl] = w.y;
      Wt[ic4 + 2][ocl] = w.z;
      Wt[ic4 + 3][ocl] = w.w;
    }
  }
  __syncthreads();

  const int ocl0 = (t >> 4) * 4;   // oc quad (broadcast read within 16-lane grp)
  const int p0   = (t & 15) * 4;   // pixel quad (keeps stores coalesced)
  float acc[4][4] = {};
#pragma unroll 4
  for (int j = 0; j < 64; ++j) {
    const float4 a  = *(const float4*)(&Wt[j][ocl0]);
    const float4 bq = *(const float4*)(&xs[j][p0]);
    const float av[4] = {a.x, a.y, a.z, a.w};
    const float bv[4] = {bq.x, bq.y, bq.z, bq.w};
#pragma unroll
    for (int i = 0; i < 4; ++i)
#pragma unroll
      for (int p = 0; p < 4; ++p)
        acc[i][p] = fmaf(av[i], bv[p], acc[i][p]);
  }
#pragma unroll
  for (int i = 0; i < 4; ++i) {
    float4 o;
    o.x = acc[i][0]; o.y = acc[i][1]; o.z = acc[i][2]; o.w = acc[i][3];
    *(float4*)(qkv1 + (size_t)(oc0 + ocl0 + i) * NPIX + n0 + p0) = o;
  }
}

// ---------------------------------------------------------------------------
// K2: depthwise 3x3 pad 1, one batch.  Block = (4-row group, ch); stages 6
// input rows in LDS (float4 coalesced), each thread computes 4 output rows
// at its column from 18 LDS reads + 36 FMA (vs 36 bounds-checked global
// loads before).  grid (64, 192).
// ---------------------------------------------------------------------------
__global__ __launch_bounds__(256) void k2_dwconv(const float* __restrict__ qkv1,
                                                 const float* __restrict__ wdw,
                                                 float* __restrict__ qkbuf,
                                                 float* __restrict__ vout) {
  const int r0 = blockIdx.x * 4;
  const int ch = blockIdx.y;
  const int t  = threadIdx.x;
  __shared__ __align__(16) float sm[6][256];
  const float* p = qkv1 + (size_t)ch * NPIX;

  // stage rows r0-1 .. r0+4 (zero rows outside the image)
  for (int idx = t; idx < 384; idx += 256) {
    const int rr = idx >> 6;
    const int c4 = (idx & 63) * 4;
    const int gr = r0 - 1 + rr;
    float4 v = make_float4(0.f, 0.f, 0.f, 0.f);
    if (gr >= 0 && gr < HWID) v = *(const float4*)(p + (size_t)gr * HWID + c4);
    *(float4*)(&sm[rr][c4]) = v;
  }
  float w[9];
#pragma unroll
  for (int i = 0; i < 9; ++i) w[i] = wdw[ch * 9 + i];
  __syncthreads();

  const int col = t;
  float cell[6][3];
#pragma unroll
  for (int rr = 0; rr < 6; ++rr) {
    cell[rr][0] = (col > 0)   ? sm[rr][col - 1] : 0.f;
    cell[rr][1] = sm[rr][col];
    cell[rr][2] = (col < 255) ? sm[rr][col + 1] : 0.f;
  }
  float* dst = (ch < 128) ? (qkbuf + (size_t)ch * NPIX)
                          : (vout + (size_t)(ch - 128) * NPIX);
#pragma unroll
  for (int k = 0; k < 4; ++k) {
    float acc = 0.f;
#pragma unroll
    for (int ky = 0; ky < 3; ++ky)
#pragma unroll
      for (int kx = 0; kx < 3; ++kx)
        acc = fmaf(w[ky * 3 + kx], cell[k + ky][kx], acc);
    dst[(size_t)(r0 + k) * HWID + col] = acc;
  }
}

// ---------------------------------------------------------------------------
// K3: Gram G[b,h][c][d] = sum_n q[c][n]*k[d][n] (+ squared norms), one batch.
// 128 n-chunks x 2 heads = 256 blocks (fills the chip; was 64).  Loads
// vectorized float4 along n: 16 VMEM per 256 FMA (was 16 per 64).
// Thread t: nt = t&15 n-lane (4 floats each); tile = t>>4 -> 8x8 (c,d) tile.
// ---------------------------------------------------------------------------
__global__ __launch_bounds__(256) void k3_gram(const float* __restrict__ qkbuf,
                                               float* __restrict__ gram,
                                               float* __restrict__ norms, int b) {
  const int chunk = blockIdx.x;   // 0..127, 512 pixels each
  const int h = blockIdx.y;       // 0..1
  const int t = threadIdx.x;
  const int nt = t & 15;
  const int tile = t >> 4;        // 0..15
  const int c0 = (tile & 3) * 8;
  const int d0 = (tile >> 2) * 8;
  const float* qb = qkbuf + (size_t)(h * 32) * NPIX;
  const float* kb = qkbuf + (size_t)(64 + h * 32) * NPIX;

  float acc[8][8] = {};
  float qn[8] = {};
  float kn[8] = {};

  const long long n0 = (long long)chunk * 512 + nt * 4;
  for (int s = 0; s < 8; ++s) {
    const long long n = n0 + s * 64;
    float4 qv[8], kv[8];
#pragma unroll
    for (int i = 0; i < 8; ++i) qv[i] = *(const float4*)(qb + (size_t)(c0 + i) * NPIX + n);
#pragma unroll
    for (int j = 0; j < 8; ++j) kv[j] = *(const float4*)(kb + (size_t)(d0 + j) * NPIX + n);
#pragma unroll
    for (int i = 0; i < 8; ++i)
#pragma unroll
      for (int j = 0; j < 8; ++j) {
        float a = acc[i][j];
        a = fmaf(qv[i].x, kv[j].x, a);
        a = fmaf(qv[i].y, kv[j].y, a);
        a = fmaf(qv[i].z, kv[j].z, a);
        a = fmaf(qv[i].w, kv[j].w, a);
        acc[i][j] = a;
      }
    if (d0 == 0) {  // tile-uniform within each 16-lane shfl group
#pragma unroll
      for (int i = 0; i < 8; ++i) {
        float a = qn[i];
        a = fmaf(qv[i].x, qv[i].x, a);
        a = fmaf(qv[i].y, qv[i].y, a);
        a = fmaf(qv[i].z, qv[i].z, a);
        a = fmaf(qv[i].w, qv[i].w, a);
        qn[i] = a;
      }
    }
    if (c0 == 0) {
#pragma unroll
      for (int j = 0; j < 8; ++j) {
        float a = kn[j];
        a = fmaf(kv[j].x, kv[j].x, a);
        a = fmaf(kv[j].y, kv[j].y, a);
        a = fmaf(kv[j].z, kv[j].z, a);
        a = fmaf(kv[j].w, kv[j].w, a);
        kn[j] = a;
      }
    }
  }

  float* gb = gram + (((size_t)b * 2 + h) * 32) * 32;
#pragma unroll
  for (int i = 0; i < 8; ++i)
#pragma unroll
    for (int j = 0; j < 8; ++j) {
      float v = acc[i][j];
      v += __shfl_xor(v, 1);
      v += __shfl_xor(v, 2);
      v += __shfl_xor(v, 4);
      v += __shfl_xor(v, 8);
      if (nt == 0) atomicAdd(&gb[(c0 + i) * 32 + (d0 + j)], v);
    }
  float* nb = norms + ((size_t)b * 2 + h) * 64;
  if (d0 == 0) {
#pragma unroll
    for (int i = 0; i < 8; ++i) {
      float v = qn[i];
      v += __shfl_xor(v, 1); v += __shfl_xor(v, 2);
      v += __shfl_xor(v, 4); v += __shfl_xor(v, 8);
      if (nt == 0) atomicAdd(&nb[c0 + i], v);
    }
  }
  if (c0 == 0) {
#pragma unroll
    for (int j = 0; j < 8; ++j) {
      float v = kn[j];
      v += __shfl_xor(v, 1); v += __shfl_xor(v, 2);
      v += __shfl_xor(v, 4); v += __shfl_xor(v, 8);
      if (nt == 0) atomicAdd(&nb[32 + d0 + j], v);
    }
  }
}

// ---------------------------------------------------------------------------
// K4: all batches.  Normalize gram -> attn; rank-based top-k (16,21,24)
// masked softmaxes; A = a1*sm1+a2*sm2+a3*sm3; fold with W_proj -> M (64x64).
// grid(8), block 256; threads <64 own one attention row each.  (unchanged)
// ---------------------------------------------------------------------------
__global__ __launch_bounds__(256) void k4_attn(const float* __restrict__ gram,
                                               const float* __restrict__ norms,
                                               const float* __restrict__ temp,
                                               const float* __restrict__ a1,
                                               const float* __restrict__ a2,
                                               const float* __restrict__ a3,
                                               const float* __restrict__ wproj,
                                               float* __restrict__ M) {
  const int b = blockIdx.x;
  const int t = threadIdx.x;
  __shared__ float A[2][32][32];
  if (t < 64) {
    const int h = t >> 5, c = t & 31;
    const float* g = gram + (((size_t)b * 2 + h) * 32 + c) * 32;
    const float* nb = norms + ((size_t)b * 2 + h) * 64;
    const float qn = fmaxf(sqrtf(nb[c]), 1e-12f);
    const float tmph = temp[h];
    float v[32];
#pragma unroll
    for (int d = 0; d < 32; ++d) {
      const float kn = fmaxf(sqrtf(nb[32 + d]), 1e-12f);
      v[d] = g[d] / (qn * kn) * tmph;
    }
    // rank(i) = #{j : v_j > v_i or (v_j == v_i and j < i)} matches top_k ties
    int rank[32];
#pragma unroll
    for (int i = 0; i < 32; ++i) {
      int r = 0;
#pragma unroll
      for (int j = 0; j < 32; ++j)
        r += (v[j] > v[i]) || (v[j] == v[i] && j < i);
      rank[i] = r;
    }
    float acc[32];
#pragma unroll
    for (int d = 0; d < 32; ++d) acc[d] = 0.f;
    const float aws[3] = {a1[0], a2[0], a3[0]};
    const int kvs[3] = {16, 21, 24};  // C/2, 2C/3, 3C/4 for C=32
#pragma unroll 1
    for (int kk = 0; kk < 3; ++kk) {
      float mx = -3.4e38f;
#pragma unroll
      for (int d = 0; d < 32; ++d)
        if (rank[d] < kvs[kk]) mx = fmaxf(mx, v[d]);
      float s = 0.f;
#pragma unroll
      for (int d = 0; d < 32; ++d)
        if (rank[d] < kvs[kk]) s += expf(v[d] - mx);
      const float inv = aws[kk] / s;
#pragma unroll
      for (int d = 0; d < 32; ++d)
        if (rank[d] < kvs[kk]) acc[d] += expf(v[d] - mx) * inv;
    }
#pragma unroll
    for (int d = 0; d < 32; ++d) A[h][c][d] = acc[d];
  }
  __syncthreads();
  // M[oc][h*32+d] = sum_c Wp[oc][h*32+c] * A[h][c][d]
  for (int e = t; e < 4096; e += 256) {
    const int oc = e >> 6, j = e & 63, h = j >> 5, d = j & 31;
    float s = 0.f;
#pragma unroll
    for (int c = 0; c < 32; ++c)
      s += wproj[oc * 64 + h * 32 + c] * A[h][c][d];
    M[(size_t)b * 4096 + e] = s;
  }
}

// ---------------------------------------------------------------------------
// K5: y[b] = M[b] (64x64) @ v[b] (64xN), all batches, IN PLACE on d_out.
// Same LDS-tiled GEMM as K1: block = 64 oc x 64 pixels, M staged (transposed)
// in LDS, v tile staged in LDS, thread = 4x4 register tile.  In-place safe:
// each block owns its 64-pixel column range exclusively and all global reads
// land in LDS before the __syncthreads / stores.  grid (1024, 8).
// ---------------------------------------------------------------------------
__global__ __launch_bounds__(256) void k5_out(float* vy,
                                              const float* __restrict__ M) {
  __shared__ __align__(16) float vs[64][LSTR];   // [j][pix]
  __shared__ __align__(16) float Mt[64][LSTR];   // [j][oc]
  const int t = threadIdx.x;
  const int b = blockIdx.y;
  const long long n0 = (long long)blockIdx.x * 64;
  float* vb = vy + (size_t)b * 64 * NPIX;
  const float* Mb = M + (size_t)b * 4096;

  {
    const int p4 = (t & 15) * 4;
#pragma unroll
    for (int r = 0; r < 4; ++r) {
      const int j = (t >> 4) + 16 * r;
      const float4 v = *(const float4*)(vb + (size_t)j * NPIX + n0 + p4);
      *(float4*)(&vs[j][p4]) = v;
    }
    const int j4 = (t & 15) * 4;
#pragma unroll
    for (int r = 0; r < 4; ++r) {
      const int oc = (t >> 4) + 16 * r;
      const float4 m = *(const float4*)(Mb + (size_t)oc * 64 + j4);
      Mt[j4 + 0][oc] = m.x;
      Mt[j4 + 1][oc] = m.y;
      Mt[j4 + 2][oc] = m.z;
      Mt[j4 + 3][oc] = m.w;
    }
  }
  __syncthreads();

  const int ocl0 = (t >> 4) * 4;
  const int p0   = (t & 15) * 4;
  float acc[4][4] = {};
#pragma unroll 4
  for (int j = 0; j < 64; ++j) {
    const float4 a  = *(const float4*)(&Mt[j][ocl0]);
    const float4 bq = *(const float4*)(&vs[j][p0]);
    const float av[4] = {a.x, a.y, a.z, a.w};
    const float bv[4] = {bq.x, bq.y, bq.z, bq.w};
#pragma unroll
    for (int i = 0; i < 4; ++i)
#pragma unroll
      for (int p = 0; p < 4; ++p)
        acc[i][p] = fmaf(av[i], bv[p], acc[i][p]);
  }
#pragma unroll
  for (int i = 0; i < 4; ++i) {
    float4 o;
    o.x = acc[i][0]; o.y = acc[i][1]; o.z = acc[i][2]; o.w = acc[i][3];
    *(float4*)(vb + (size_t)(ocl0 + i) * NPIX + n0 + p0) = o;
  }
}

extern "C" void kernel_launch(void* const* d_in, const int* in_sizes, int n_in,
                              void* d_out, int out_size, void* d_ws, size_t ws_size,
                              hipStream_t stream) {
  const float* x     = (const float*)d_in[0];
  const float* wqkv  = (const float*)d_in[1];
  const float* wdw   = (const float*)d_in[2];
  const float* wproj = (const float*)d_in[3];
  const float* temp  = (const float*)d_in[4];
  const float* a1    = (const float*)d_in[5];
  const float* a2    = (const float*)d_in[6];
  const float* a3    = (const float*)d_in[7];

  float* ws    = (float*)d_ws;
  float* qkv1b = ws + OFF_QKV1B;
  float* qkb   = ws + OFF_QKB;
  float* gram  = ws + OFF_GRAM;
  float* norms = ws + OFF_NORM;
  float* M     = ws + OFF_M;
  float* y     = (float*)d_out;

  // zero the atomic accumulators (gram + norms contiguous)
  hipMemsetAsync(gram, 0, (SZ_GRAM + SZ_NORM) * sizeof(float), stream);

  dim3 blk(256);
  for (int b = 0; b < B_; ++b) {
    k1_qkv1x1<<<dim3(1024, 3), blk, 0, stream>>>(x, wqkv, qkv1b, b);
    k2_dwconv<<<dim3(64, C3), blk, 0, stream>>>(
        qkv1b, wdw, qkb, y + (size_t)b * 64 * NPIX);
    k3_gram<<<dim3(128, 2), blk, 0, stream>>>(qkb, gram, norms, b);
  }
  k4_attn<<<dim3(B_), blk, 0, stream>>>(gram, norms, temp, a1, a2, a3, wproj, M);
  k5_out<<<dim3(1024, B_), blk, 0, stream>>>(y, M);
}

// Round 2
// 808.198 us; speedup vs baseline: 2.4346x; 2.0808x over previous
//
#include <hip/hip_runtime.h>
#include <math.h>

// Problem constants (fixed by setup_inputs)
constexpr int B_   = 8;
constexpr int CIN  = 64;     // dim
constexpr int C3   = 192;    // 3*dim
constexpr int HWID = 256;
constexpr long long NPIX = 65536; // 256*256

// k3 partial-reduction geometry
constexpr int K3_CHUNKS = 128;   // 512 pixels per chunk
constexpr int K3_CELLS  = 1088;  // 1024 gram + 32 qn + 32 kn

// Per-batch workspace layout (floats) — total ~23.3M floats (~93 MB)
constexpr size_t SZ_QKV1B = (size_t)C3 * NPIX;         // [192][65536] 1x1 out, one batch
constexpr size_t SZ_QKB   = (size_t)128 * NPIX;        // [128][65536] dw q,k one batch
constexpr size_t OFF_QKV1B = 0;
constexpr size_t OFF_QKB   = OFF_QKV1B + SZ_QKV1B;
constexpr size_t OFF_GRAM  = OFF_QKB + SZ_QKB;         // [8][2][32][32]
constexpr size_t SZ_GRAM   = (size_t)B_ * 2 * 32 * 32;
constexpr size_t OFF_NORM  = OFF_GRAM + SZ_GRAM;       // [8][2][64]
constexpr size_t SZ_NORM   = (size_t)B_ * 2 * 64;
constexpr size_t OFF_M     = OFF_NORM + SZ_NORM;       // [8][64][64]
constexpr size_t SZ_M      = (size_t)B_ * 64 * 64;
constexpr size_t OFF_PART  = OFF_M + SZ_M;             // [8][2][128][1088]
constexpr size_t SZ_PART   = (size_t)B_ * 2 * K3_CHUNKS * K3_CELLS;

// LDS tile stride: 68 floats = 272 B, keeps row starts 16B-aligned for
// ds_read_b128 while breaking the 64-float power-of-2 bank pattern.
constexpr int LSTR = 68;

// ---------------------------------------------------------------------------
// K1: qkv1 = W_qkv (192x64) @ x_b (64xN), one batch.  LDS-tiled GEMM:
// block = 64 oc x 64 pixels, thread = 4x4 register tile.
// grid (NPIX/64 = 1024, 3 oc-tiles).
// ---------------------------------------------------------------------------
__global__ __launch_bounds__(256) void k1_qkv1x1(const float* __restrict__ x,
                                                 const float* __restrict__ wqkv,
                                                 float* __restrict__ qkv1, int b) {
  __shared__ __align__(16) float xs[64][LSTR];   // [ic][pix]
  __shared__ __align__(16) float Wt[64][LSTR];   // [ic][oc]  (transposed W)
  const int t = threadIdx.x;
  const long long n0 = (long long)blockIdx.x * 64;
  const int oc0 = blockIdx.y * 64;
  const float* xb = x + (size_t)b * CIN * NPIX;

  {
    const int p4 = (t & 15) * 4;
#pragma unroll
    for (int r = 0; r < 4; ++r) {
      const int ic = (t >> 4) + 16 * r;
      const float4 v = *(const float4*)(xb + (size_t)ic * NPIX + n0 + p4);
      *(float4*)(&xs[ic][p4]) = v;
    }
    const int ic4 = (t & 15) * 4;
#pragma unroll
    for (int r = 0; r < 4; ++r) {
      const int ocl = (t >> 4) + 16 * r;
      const float4 w = *(const float4*)(wqkv + (size_t)(oc0 + ocl) * 64 + ic4);
      Wt[ic4 + 0][ocl] = w.x;
      Wt[ic4 + 1][ocl] = w.y;
      Wt[ic4 + 2][ocl] = w.z;
      Wt[ic4 + 3][ocl] = w.w;
    }
  }
  __syncthreads();

  const int ocl0 = (t >> 4) * 4;
  const int p0   = (t & 15) * 4;
  float acc[4][4] = {};
#pragma unroll 4
  for (int j = 0; j < 64; ++j) {
    const float4 a  = *(const float4*)(&Wt[j][ocl0]);
    const float4 bq = *(const float4*)(&xs[j][p0]);
    const float av[4] = {a.x, a.y, a.z, a.w};
    const float bv[4] = {bq.x, bq.y, bq.z, bq.w};
#pragma unroll
    for (int i = 0; i < 4; ++i)
#pragma unroll
      for (int p = 0; p < 4; ++p)
        acc[i][p] = fmaf(av[i], bv[p], acc[i][p]);
  }
#pragma unroll
  for (int i = 0; i < 4; ++i) {
    float4 o;
    o.x = acc[i][0]; o.y = acc[i][1]; o.z = acc[i][2]; o.w = acc[i][3];
    *(float4*)(qkv1 + (size_t)(oc0 + ocl0 + i) * NPIX + n0 + p0) = o;
  }
}

// ---------------------------------------------------------------------------
// K2: depthwise 3x3 pad 1, one batch.  Block = (4-row group, ch); stages 6
// input rows in LDS, each thread computes 4 output rows at its column.
// grid (64, 192).
// ---------------------------------------------------------------------------
__global__ __launch_bounds__(256) void k2_dwconv(const float* __restrict__ qkv1,
                                                 const float* __restrict__ wdw,
                                                 float* __restrict__ qkbuf,
                                                 float* __restrict__ vout) {
  const int r0 = blockIdx.x * 4;
  const int ch = blockIdx.y;
  const int t  = threadIdx.x;
  __shared__ __align__(16) float sm[6][256];
  const float* p = qkv1 + (size_t)ch * NPIX;

  for (int idx = t; idx < 384; idx += 256) {
    const int rr = idx >> 6;
    const int c4 = (idx & 63) * 4;
    const int gr = r0 - 1 + rr;
    float4 v = make_float4(0.f, 0.f, 0.f, 0.f);
    if (gr >= 0 && gr < HWID) v = *(const float4*)(p + (size_t)gr * HWID + c4);
    *(float4*)(&sm[rr][c4]) = v;
  }
  float w[9];
#pragma unroll
  for (int i = 0; i < 9; ++i) w[i] = wdw[ch * 9 + i];
  __syncthreads();

  const int col = t;
  float cell[6][3];
#pragma unroll
  for (int rr = 0; rr < 6; ++rr) {
    cell[rr][0] = (col > 0)   ? sm[rr][col - 1] : 0.f;
    cell[rr][1] = sm[rr][col];
    cell[rr][2] = (col < 255) ? sm[rr][col + 1] : 0.f;
  }
  float* dst = (ch < 128) ? (qkbuf + (size_t)ch * NPIX)
                          : (vout + (size_t)(ch - 128) * NPIX);
#pragma unroll
  for (int k = 0; k < 4; ++k) {
    float acc = 0.f;
#pragma unroll
    for (int ky = 0; ky < 3; ++ky)
#pragma unroll
      for (int kx = 0; kx < 3; ++kx)
        acc = fmaf(w[ky * 3 + kx], cell[k + ky][kx], acc);
    dst[(size_t)(r0 + k) * HWID + col] = acc;
  }
}

// ---------------------------------------------------------------------------
// K3: Gram partials, one batch.  REDESIGNED (R2): per-thread tile 8x8 -> 4x4
// (no register starvation), block = 1024 threads = full 32x32 gram
// (64 tiles x 16 n-lanes), grid 128 chunks x 2 heads = 256 blocks of 16
// waves -> 16 waves/CU (was 1 wave/SIMD).  Contended atomics replaced by
// per-block partial buffers reduced in k3_reduce.
// ---------------------------------------------------------------------------
__global__ __launch_bounds__(1024) void k3_gram(const float* __restrict__ qkbuf,
                                                float* __restrict__ part, int b) {
  const int chunk = blockIdx.x;   // 0..127, 512 pixels each
  const int h = blockIdx.y;       // 0..1
  const int t = threadIdx.x;      // 0..1023
  const int nt = t & 15;
  const int tile = t >> 4;        // 0..63
  const int c0 = (tile & 7) * 4;
  const int d0 = (tile >> 3) * 4;
  const bool do_qn = (d0 == 0);   // tiles 0..7 cover all c
  const bool do_kn = (c0 == 0);   // tiles 0,8,..,56 cover all d
  const float* qb = qkbuf + (size_t)(h * 32) * NPIX;
  const float* kb = qkbuf + (size_t)(64 + h * 32) * NPIX;

  float acc[4][4] = {};
  float qn[4] = {}, kn[4] = {};
  const long long n0 = (long long)chunk * 512 + nt * 4;
#pragma unroll 2
  for (int s = 0; s < 8; ++s) {
    const long long n = n0 + (long long)s * 64;
    float4 qv[4], kv[4];
#pragma unroll
    for (int i = 0; i < 4; ++i)
      qv[i] = *(const float4*)(qb + (size_t)(c0 + i) * NPIX + n);
#pragma unroll
    for (int j = 0; j < 4; ++j)
      kv[j] = *(const float4*)(kb + (size_t)(d0 + j) * NPIX + n);
#pragma unroll
    for (int i = 0; i < 4; ++i)
#pragma unroll
      for (int j = 0; j < 4; ++j) {
        float a = acc[i][j];
        a = fmaf(qv[i].x, kv[j].x, a);
        a = fmaf(qv[i].y, kv[j].y, a);
        a = fmaf(qv[i].z, kv[j].z, a);
        a = fmaf(qv[i].w, kv[j].w, a);
        acc[i][j] = a;
      }
    if (do_qn) {
#pragma unroll
      for (int i = 0; i < 4; ++i) {
        float a = qn[i];
        a = fmaf(qv[i].x, qv[i].x, a);
        a = fmaf(qv[i].y, qv[i].y, a);
        a = fmaf(qv[i].z, qv[i].z, a);
        a = fmaf(qv[i].w, qv[i].w, a);
        qn[i] = a;
      }
    }
    if (do_kn) {
#pragma unroll
      for (int j = 0; j < 4; ++j) {
        float a = kn[j];
        a = fmaf(kv[j].x, kv[j].x, a);
        a = fmaf(kv[j].y, kv[j].y, a);
        a = fmaf(kv[j].z, kv[j].z, a);
        a = fmaf(kv[j].w, kv[j].w, a);
        kn[j] = a;
      }
    }
  }

  // reduce over the 16 n-lanes (xor masks < 16 stay within a tile's group)
  float* pb = part + (((size_t)(b * 2 + h)) * K3_CHUNKS + chunk) * K3_CELLS;
#pragma unroll
  for (int i = 0; i < 4; ++i)
#pragma unroll
    for (int j = 0; j < 4; ++j) {
      float v = acc[i][j];
      v += __shfl_xor(v, 1); v += __shfl_xor(v, 2);
      v += __shfl_xor(v, 4); v += __shfl_xor(v, 8);
      if (nt == 0) pb[(c0 + i) * 32 + (d0 + j)] = v;
    }
  if (do_qn) {
#pragma unroll
    for (int i = 0; i < 4; ++i) {
      float v = qn[i];
      v += __shfl_xor(v, 1); v += __shfl_xor(v, 2);
      v += __shfl_xor(v, 4); v += __shfl_xor(v, 8);
      if (nt == 0) pb[1024 + c0 + i] = v;
    }
  }
  if (do_kn) {
#pragma unroll
    for (int j = 0; j < 4; ++j) {
      float v = kn[j];
      v += __shfl_xor(v, 1); v += __shfl_xor(v, 2);
      v += __shfl_xor(v, 4); v += __shfl_xor(v, 8);
      if (nt == 0) pb[1056 + d0 + j] = v;
    }
  }
}

// ---------------------------------------------------------------------------
// K3R: sum chunk partials -> gram/norms for all batches.  grid 68 x 256
// threads = 17408 = 8*2*1088 cells; each thread strides 128 chunks.
// ---------------------------------------------------------------------------
__global__ __launch_bounds__(256) void k3_reduce(const float* __restrict__ part,
                                                 float* __restrict__ gram,
                                                 float* __restrict__ norms) {
  const int e = blockIdx.x * 256 + threadIdx.x;   // 0..17407
  const int bh = e / K3_CELLS;                    // 0..15
  const int cell = e - bh * K3_CELLS;
  const float* p = part + ((size_t)bh * K3_CHUNKS) * K3_CELLS + cell;
  float s0 = 0.f, s1 = 0.f;
#pragma unroll 4
  for (int ch = 0; ch < K3_CHUNKS; ch += 2) {
    s0 += p[(size_t)ch * K3_CELLS];
    s1 += p[(size_t)(ch + 1) * K3_CELLS];
  }
  const float s = s0 + s1;
  if (cell < 1024) gram[(size_t)bh * 1024 + cell] = s;
  else             norms[(size_t)bh * 64 + (cell - 1024)] = s;
}

// ---------------------------------------------------------------------------
// K4: all batches.  Normalize gram -> attn; rank-based top-k (16,21,24)
// masked softmaxes; fold with W_proj -> M (64x64).  (unchanged)
// ---------------------------------------------------------------------------
__global__ __launch_bounds__(256) void k4_attn(const float* __restrict__ gram,
                                               const float* __restrict__ norms,
                                               const float* __restrict__ temp,
                                               const float* __restrict__ a1,
                                               const float* __restrict__ a2,
                                               const float* __restrict__ a3,
                                               const float* __restrict__ wproj,
                                               float* __restrict__ M) {
  const int b = blockIdx.x;
  const int t = threadIdx.x;
  __shared__ float A[2][32][32];
  if (t < 64) {
    const int h = t >> 5, c = t & 31;
    const float* g = gram + (((size_t)b * 2 + h) * 32 + c) * 32;
    const float* nb = norms + ((size_t)b * 2 + h) * 64;
    const float qn = fmaxf(sqrtf(nb[c]), 1e-12f);
    const float tmph = temp[h];
    float v[32];
#pragma unroll
    for (int d = 0; d < 32; ++d) {
      const float kn = fmaxf(sqrtf(nb[32 + d]), 1e-12f);
      v[d] = g[d] / (qn * kn) * tmph;
    }
    int rank[32];
#pragma unroll
    for (int i = 0; i < 32; ++i) {
      int r = 0;
#pragma unroll
      for (int j = 0; j < 32; ++j)
        r += (v[j] > v[i]) || (v[j] == v[i] && j < i);
      rank[i] = r;
    }
    float acc[32];
#pragma unroll
    for (int d = 0; d < 32; ++d) acc[d] = 0.f;
    const float aws[3] = {a1[0], a2[0], a3[0]};
    const int kvs[3] = {16, 21, 24};  // C/2, 2C/3, 3C/4 for C=32
#pragma unroll 1
    for (int kk = 0; kk < 3; ++kk) {
      float mx = -3.4e38f;
#pragma unroll
      for (int d = 0; d < 32; ++d)
        if (rank[d] < kvs[kk]) mx = fmaxf(mx, v[d]);
      float s = 0.f;
#pragma unroll
      for (int d = 0; d < 32; ++d)
        if (rank[d] < kvs[kk]) s += expf(v[d] - mx);
      const float inv = aws[kk] / s;
#pragma unroll
      for (int d = 0; d < 32; ++d)
        if (rank[d] < kvs[kk]) acc[d] += expf(v[d] - mx) * inv;
    }
#pragma unroll
    for (int d = 0; d < 32; ++d) A[h][c][d] = acc[d];
  }
  __syncthreads();
  for (int e = t; e < 4096; e += 256) {
    const int oc = e >> 6, j = e & 63, h = j >> 5, d = j & 31;
    float s = 0.f;
#pragma unroll
    for (int c = 0; c < 32; ++c)
      s += wproj[oc * 64 + h * 32 + c] * A[h][c][d];
    M[(size_t)b * 4096 + e] = s;
  }
}

// ---------------------------------------------------------------------------
// K5: y[b] = M[b] (64x64) @ v[b] (64xN), all batches, IN PLACE on d_out.
// LDS-tiled GEMM, block = 64 oc x 64 pixels, thread = 4x4.  grid (1024, 8).
// ---------------------------------------------------------------------------
__global__ __launch_bounds__(256) void k5_out(float* vy,
                                              const float* __restrict__ M) {
  __shared__ __align__(16) float vs[64][LSTR];   // [j][pix]
  __shared__ __align__(16) float Mt[64][LSTR];   // [j][oc]
  const int t = threadIdx.x;
  const int b = blockIdx.y;
  const long long n0 = (long long)blockIdx.x * 64;
  float* vb = vy + (size_t)b * 64 * NPIX;
  const float* Mb = M + (size_t)b * 4096;

  {
    const int p4 = (t & 15) * 4;
#pragma unroll
    for (int r = 0; r < 4; ++r) {
      const int j = (t >> 4) + 16 * r;
      const float4 v = *(const float4*)(vb + (size_t)j * NPIX + n0 + p4);
      *(float4*)(&vs[j][p4]) = v;
    }
    const int j4 = (t & 15) * 4;
#pragma unroll
    for (int r = 0; r < 4; ++r) {
      const int oc = (t >> 4) + 16 * r;
      const float4 m = *(const float4*)(Mb + (size_t)oc * 64 + j4);
      Mt[j4 + 0][oc] = m.x;
      Mt[j4 + 1][oc] = m.y;
      Mt[j4 + 2][oc] = m.z;
      Mt[j4 + 3][oc] = m.w;
    }
  }
  __syncthreads();

  const int ocl0 = (t >> 4) * 4;
  const int p0   = (t & 15) * 4;
  float acc[4][4] = {};
#pragma unroll 4
  for (int j = 0; j < 64; ++j) {
    const float4 a  = *(const float4*)(&Mt[j][ocl0]);
    const float4 bq = *(const float4*)(&vs[j][p0]);
    const float av[4] = {a.x, a.y, a.z, a.w};
    const float bv[4] = {bq.x, bq.y, bq.z, bq.w};
#pragma unroll
    for (int i = 0; i < 4; ++i)
#pragma unroll
      for (int p = 0; p < 4; ++p)
        acc[i][p] = fmaf(av[i], bv[p], acc[i][p]);
  }
#pragma unroll
  for (int i = 0; i < 4; ++i) {
    float4 o;
    o.x = acc[i][0]; o.y = acc[i][1]; o.z = acc[i][2]; o.w = acc[i][3];
    *(float4*)(vb + (size_t)(ocl0 + i) * NPIX + n0 + p0) = o;
  }
}

extern "C" void kernel_launch(void* const* d_in, const int* in_sizes, int n_in,
                              void* d_out, int out_size, void* d_ws, size_t ws_size,
                              hipStream_t stream) {
  const float* x     = (const float*)d_in[0];
  const float* wqkv  = (const float*)d_in[1];
  const float* wdw   = (const float*)d_in[2];
  const float* wproj = (const float*)d_in[3];
  const float* temp  = (const float*)d_in[4];
  const float* a1    = (const float*)d_in[5];
  const float* a2    = (const float*)d_in[6];
  const float* a3    = (const float*)d_in[7];

  float* ws    = (float*)d_ws;
  float* qkv1b = ws + OFF_QKV1B;
  float* qkb   = ws + OFF_QKB;
  float* gram  = ws + OFF_GRAM;
  float* norms = ws + OFF_NORM;
  float* M     = ws + OFF_M;
  float* part  = ws + OFF_PART;
  float* y     = (float*)d_out;

  dim3 blk(256);
  for (int b = 0; b < B_; ++b) {
    k1_qkv1x1<<<dim3(1024, 3), blk, 0, stream>>>(x, wqkv, qkv1b, b);
    k2_dwconv<<<dim3(64, C3), blk, 0, stream>>>(
        qkv1b, wdw, qkb, y + (size_t)b * 64 * NPIX);
    k3_gram<<<dim3(K3_CHUNKS, 2), dim3(1024), 0, stream>>>(qkb, part, b);
  }
  k3_reduce<<<dim3(68), blk, 0, stream>>>(part, gram, norms);
  k4_attn<<<dim3(B_), blk, 0, stream>>>(gram, norms, temp, a1, a2, a3, wproj, M);
  k5_out<<<dim3(1024, B_), blk, 0, stream>>>(y, M);
}

// Round 3
// 761.830 us; speedup vs baseline: 2.5828x; 1.0609x over previous
//
#include <hip/hip_runtime.h>
#include <math.h>

// Problem constants (fixed by setup_inputs)
constexpr int B_   = 8;
constexpr int CIN  = 64;     // dim
constexpr int C3   = 192;    // 3*dim
constexpr int HWID = 256;
constexpr long long NPIX = 65536; // 256*256

// k3 partial-reduction geometry
constexpr int K3_CHUNKS = 128;   // 512 pixels per chunk
constexpr int K3_CELLS  = 1088;  // 1024 gram + 32 qn + 32 kn

// Per-batch buffer sizes (floats)
constexpr size_t SZ_QKV1_1B = (size_t)C3 * NPIX;   // 12.58M  (one batch, 192ch)
constexpr size_t SZ_QKB_1B  = (size_t)128 * NPIX;  //  8.39M  (one batch, q+k)
constexpr size_t SZ_GRAM = (size_t)B_ * 2 * 32 * 32;
constexpr size_t SZ_NORM = (size_t)B_ * 2 * 64;
constexpr size_t SZ_M    = (size_t)B_ * 64 * 64;
constexpr size_t SZ_PART = (size_t)B_ * 2 * K3_CHUNKS * K3_CELLS;

// LDS tile stride for the GEMM kernels
constexpr int LSTR = 68;

// ---------------------------------------------------------------------------
// K1: qkv1 = W_qkv (192x64) @ x_b (64xN).  LDS-tiled GEMM, thread = 4x4 tile.
// grid (1024, 3 oc-tiles, nb local batches).  Writes qkv1[lb].
// ---------------------------------------------------------------------------
__global__ __launch_bounds__(256) void k1_qkv1x1(const float* __restrict__ x,
                                                 const float* __restrict__ wqkv,
                                                 float* __restrict__ qkv1, int b0) {
  __shared__ __align__(16) float xs[64][LSTR];   // [ic][pix]
  __shared__ __align__(16) float Wt[64][LSTR];   // [ic][oc]  (transposed W)
  const int t = threadIdx.x;
  const int lb = blockIdx.z;
  const long long n0 = (long long)blockIdx.x * 64;
  const int oc0 = blockIdx.y * 64;
  const float* xb = x + (size_t)(b0 + lb) * CIN * NPIX;
  float* outb = qkv1 + (size_t)lb * SZ_QKV1_1B;

  {
    const int p4 = (t & 15) * 4;
#pragma unroll
    for (int r = 0; r < 4; ++r) {
      const int ic = (t >> 4) + 16 * r;
      const float4 v = *(const float4*)(xb + (size_t)ic * NPIX + n0 + p4);
      *(float4*)(&xs[ic][p4]) = v;
    }
    const int ic4 = (t & 15) * 4;
#pragma unroll
    for (int r = 0; r < 4; ++r) {
      const int ocl = (t >> 4) + 16 * r;
      const float4 w = *(const float4*)(wqkv + (size_t)(oc0 + ocl) * 64 + ic4);
      Wt[ic4 + 0][ocl] = w.x;
      Wt[ic4 + 1][ocl] = w.y;
      Wt[ic4 + 2][ocl] = w.z;
      Wt[ic4 + 3][ocl] = w.w;
    }
  }
  __syncthreads();

  const int ocl0 = (t >> 4) * 4;
  const int p0   = (t & 15) * 4;
  float acc[4][4] = {};
#pragma unroll 4
  for (int j = 0; j < 64; ++j) {
    const float4 a  = *(const float4*)(&Wt[j][ocl0]);
    const float4 bq = *(const float4*)(&xs[j][p0]);
    const float av[4] = {a.x, a.y, a.z, a.w};
    const float bv[4] = {bq.x, bq.y, bq.z, bq.w};
#pragma unroll
    for (int i = 0; i < 4; ++i)
#pragma unroll
      for (int p = 0; p < 4; ++p)
        acc[i][p] = fmaf(av[i], bv[p], acc[i][p]);
  }
#pragma unroll
  for (int i = 0; i < 4; ++i) {
    float4 o;
    o.x = acc[i][0]; o.y = acc[i][1]; o.z = acc[i][2]; o.w = acc[i][3];
    *(float4*)(outb + (size_t)(oc0 + ocl0 + i) * NPIX + n0 + p0) = o;
  }
}

// ---------------------------------------------------------------------------
// K2: depthwise 3x3 pad 1.  R3: 16 output rows/block (stage 18 rows: halo
// re-read 1.5x -> 1.125x), rolling 3-row register window: 3 LDS reads +
// 9 FMA per output row.  grid (16, 192, nb).
// qkb/vout are HALF-base pointers; kernel adds lb*stride.
// ---------------------------------------------------------------------------
__global__ __launch_bounds__(256) void k2_dwconv(const float* __restrict__ qkv1,
                                                 const float* __restrict__ wdw,
                                                 float* __restrict__ qkb,
                                                 size_t qkb_stride,
                                                 float* __restrict__ vout) {
  const int r0 = blockIdx.x * 16;
  const int ch = blockIdx.y;
  const int lb = blockIdx.z;
  const int t  = threadIdx.x;
  __shared__ __align__(16) float sm[18][256];
  const float* p = qkv1 + (size_t)lb * SZ_QKV1_1B + (size_t)ch * NPIX;

  // stage rows r0-1 .. r0+16 (zero rows outside the image)
  for (int idx = t; idx < 18 * 64; idx += 256) {
    const int rr = idx >> 6;
    const int c4 = (idx & 63) * 4;
    const int gr = r0 - 1 + rr;
    float4 v = make_float4(0.f, 0.f, 0.f, 0.f);
    if (gr >= 0 && gr < HWID) v = *(const float4*)(p + (size_t)gr * HWID + c4);
    *(float4*)(&sm[rr][c4]) = v;
  }
  float w[9];
#pragma unroll
  for (int i = 0; i < 9; ++i) w[i] = wdw[ch * 9 + i];
  __syncthreads();

  const int col = t;
  const bool cl = (col > 0), cr = (col < 255);
  float l0 = cl ? sm[0][col - 1] : 0.f, m0 = sm[0][col], r0v = cr ? sm[0][col + 1] : 0.f;
  float l1 = cl ? sm[1][col - 1] : 0.f, m1 = sm[1][col], r1v = cr ? sm[1][col + 1] : 0.f;
  float* dst = (ch < 128)
                   ? (qkb + (size_t)lb * qkb_stride + (size_t)ch * NPIX)
                   : (vout + (size_t)lb * 64 * NPIX + (size_t)(ch - 128) * NPIX);
#pragma unroll
  for (int k = 0; k < 16; ++k) {
    const float l2 = cl ? sm[k + 2][col - 1] : 0.f;
    const float m2 = sm[k + 2][col];
    const float r2v = cr ? sm[k + 2][col + 1] : 0.f;
    float acc = w[0] * l0;
    acc = fmaf(w[1], m0, acc);  acc = fmaf(w[2], r0v, acc);
    acc = fmaf(w[3], l1, acc);  acc = fmaf(w[4], m1, acc);
    acc = fmaf(w[5], r1v, acc); acc = fmaf(w[6], l2, acc);
    acc = fmaf(w[7], m2, acc);  acc = fmaf(w[8], r2v, acc);
    dst[(size_t)(r0 + k) * HWID + col] = acc;
    l0 = l1; m0 = m1; r0v = r1v;
    l1 = l2; m1 = m2; r1v = r2v;
  }
}

// ---------------------------------------------------------------------------
// K3: Gram partials.  Block = 1024 thr = full 32x32 gram (64 tiles x 16
// n-lanes), per-thread 4x4 tile, per-block partial buffers (no atomics).
// grid (128 chunks, 2 heads, nb).  b = b0 + blockIdx.z; qkb batch stride arg.
// ---------------------------------------------------------------------------
__global__ __launch_bounds__(1024) void k3_gram(const float* __restrict__ qkbuf,
                                                size_t qkb_stride,
                                                float* __restrict__ part, int b0) {
  const int chunk = blockIdx.x;   // 0..127, 512 pixels each
  const int h = blockIdx.y;       // 0..1
  const int lb = blockIdx.z;
  const int b = b0 + lb;
  const int t = threadIdx.x;      // 0..1023
  const int nt = t & 15;
  const int tile = t >> 4;        // 0..63
  const int c0 = (tile & 7) * 4;
  const int d0 = (tile >> 3) * 4;
  const bool do_qn = (d0 == 0);
  const bool do_kn = (c0 == 0);
  const float* base = qkbuf + (size_t)lb * qkb_stride;
  const float* qb = base + (size_t)(h * 32) * NPIX;
  const float* kb = base + (size_t)(64 + h * 32) * NPIX;

  float acc[4][4] = {};
  float qn[4] = {}, kn[4] = {};
  const long long n0 = (long long)chunk * 512 + nt * 4;
#pragma unroll 2
  for (int s = 0; s < 8; ++s) {
    const long long n = n0 + (long long)s * 64;
    float4 qv[4], kv[4];
#pragma unroll
    for (int i = 0; i < 4; ++i)
      qv[i] = *(const float4*)(qb + (size_t)(c0 + i) * NPIX + n);
#pragma unroll
    for (int j = 0; j < 4; ++j)
      kv[j] = *(const float4*)(kb + (size_t)(d0 + j) * NPIX + n);
#pragma unroll
    for (int i = 0; i < 4; ++i)
#pragma unroll
      for (int j = 0; j < 4; ++j) {
        float a = acc[i][j];
        a = fmaf(qv[i].x, kv[j].x, a);
        a = fmaf(qv[i].y, kv[j].y, a);
        a = fmaf(qv[i].z, kv[j].z, a);
        a = fmaf(qv[i].w, kv[j].w, a);
        acc[i][j] = a;
      }
    if (do_qn) {
#pragma unroll
      for (int i = 0; i < 4; ++i) {
        float a = qn[i];
        a = fmaf(qv[i].x, qv[i].x, a);
        a = fmaf(qv[i].y, qv[i].y, a);
        a = fmaf(qv[i].z, qv[i].z, a);
        a = fmaf(qv[i].w, qv[i].w, a);
        qn[i] = a;
      }
    }
    if (do_kn) {
#pragma unroll
      for (int j = 0; j < 4; ++j) {
        float a = kn[j];
        a = fmaf(kv[j].x, kv[j].x, a);
        a = fmaf(kv[j].y, kv[j].y, a);
        a = fmaf(kv[j].z, kv[j].z, a);
        a = fmaf(kv[j].w, kv[j].w, a);
        kn[j] = a;
      }
    }
  }

  float* pb = part + (((size_t)(b * 2 + h)) * K3_CHUNKS + chunk) * K3_CELLS;
#pragma unroll
  for (int i = 0; i < 4; ++i)
#pragma unroll
    for (int j = 0; j < 4; ++j) {
      float v = acc[i][j];
      v += __shfl_xor(v, 1); v += __shfl_xor(v, 2);
      v += __shfl_xor(v, 4); v += __shfl_xor(v, 8);
      if (nt == 0) pb[(c0 + i) * 32 + (d0 + j)] = v;
    }
  if (do_qn) {
#pragma unroll
    for (int i = 0; i < 4; ++i) {
      float v = qn[i];
      v += __shfl_xor(v, 1); v += __shfl_xor(v, 2);
      v += __shfl_xor(v, 4); v += __shfl_xor(v, 8);
      if (nt == 0) pb[1024 + c0 + i] = v;
    }
  }
  if (do_kn) {
#pragma unroll
    for (int j = 0; j < 4; ++j) {
      float v = kn[j];
      v += __shfl_xor(v, 1); v += __shfl_xor(v, 2);
      v += __shfl_xor(v, 4); v += __shfl_xor(v, 8);
      if (nt == 0) pb[1056 + d0 + j] = v;
    }
  }
}

// ---------------------------------------------------------------------------
// K3R: sum chunk partials -> gram/norms, all batches.  grid 68 x 256.
// ---------------------------------------------------------------------------
__global__ __launch_bounds__(256) void k3_reduce(const float* __restrict__ part,
                                                 float* __restrict__ gram,
                                                 float* __restrict__ norms) {
  const int e = blockIdx.x * 256 + threadIdx.x;   // 0..17407
  const int bh = e / K3_CELLS;                    // 0..15
  const int cell = e - bh * K3_CELLS;
  const float* p = part + ((size_t)bh * K3_CHUNKS) * K3_CELLS + cell;
  float s0 = 0.f, s1 = 0.f;
#pragma unroll 4
  for (int ch = 0; ch < K3_CHUNKS; ch += 2) {
    s0 += p[(size_t)ch * K3_CELLS];
    s1 += p[(size_t)(ch + 1) * K3_CELLS];
  }
  const float s = s0 + s1;
  if (cell < 1024) gram[(size_t)bh * 1024 + cell] = s;
  else             norms[(size_t)bh * 64 + (cell - 1024)] = s;
}

// ---------------------------------------------------------------------------
// K4: normalize gram -> attn; rank-based top-k (16,21,24) masked softmaxes;
// fold with W_proj -> M (64x64).  (unchanged)
// ---------------------------------------------------------------------------
__global__ __launch_bounds__(256) void k4_attn(const float* __restrict__ gram,
                                               const float* __restrict__ norms,
                                               const float* __restrict__ temp,
                                               const float* __restrict__ a1,
                                               const float* __restrict__ a2,
                                               const float* __restrict__ a3,
                                               const float* __restrict__ wproj,
                                               float* __restrict__ M) {
  const int b = blockIdx.x;
  const int t = threadIdx.x;
  __shared__ float A[2][32][32];
  if (t < 64) {
    const int h = t >> 5, c = t & 31;
    const float* g = gram + (((size_t)b * 2 + h) * 32 + c) * 32;
    const float* nb = norms + ((size_t)b * 2 + h) * 64;
    const float qn = fmaxf(sqrtf(nb[c]), 1e-12f);
    const float tmph = temp[h];
    float v[32];
#pragma unroll
    for (int d = 0; d < 32; ++d) {
      const float kn = fmaxf(sqrtf(nb[32 + d]), 1e-12f);
      v[d] = g[d] / (qn * kn) * tmph;
    }
    int rank[32];
#pragma unroll
    for (int i = 0; i < 32; ++i) {
      int r = 0;
#pragma unroll
      for (int j = 0; j < 32; ++j)
        r += (v[j] > v[i]) || (v[j] == v[i] && j < i);
      rank[i] = r;
    }
    float acc[32];
#pragma unroll
    for (int d = 0; d < 32; ++d) acc[d] = 0.f;
    const float aws[3] = {a1[0], a2[0], a3[0]};
    const int kvs[3] = {16, 21, 24};  // C/2, 2C/3, 3C/4 for C=32
#pragma unroll 1
    for (int kk = 0; kk < 3; ++kk) {
      float mx = -3.4e38f;
#pragma unroll
      for (int d = 0; d < 32; ++d)
        if (rank[d] < kvs[kk]) mx = fmaxf(mx, v[d]);
      float s = 0.f;
#pragma unroll
      for (int d = 0; d < 32; ++d)
        if (rank[d] < kvs[kk]) s += expf(v[d] - mx);
      const float inv = aws[kk] / s;
#pragma unroll
      for (int d = 0; d < 32; ++d)
        if (rank[d] < kvs[kk]) acc[d] += expf(v[d] - mx) * inv;
    }
#pragma unroll
    for (int d = 0; d < 32; ++d) A[h][c][d] = acc[d];
  }
  __syncthreads();
  for (int e = t; e < 4096; e += 256) {
    const int oc = e >> 6, j = e & 63, h = j >> 5, d = j & 31;
    float s = 0.f;
#pragma unroll
    for (int c = 0; c < 32; ++c)
      s += wproj[oc * 64 + h * 32 + c] * A[h][c][d];
    M[(size_t)b * 4096 + e] = s;
  }
}

// ---------------------------------------------------------------------------
// K5: y[b] = M[b] (64x64) @ v[b] (64xN), IN PLACE on d_out.  LDS-tiled GEMM.
// grid (1024, 8).
// ---------------------------------------------------------------------------
__global__ __launch_bounds__(256) void k5_out(float* vy,
                                              const float* __restrict__ M) {
  __shared__ __align__(16) float vs[64][LSTR];   // [j][pix]
  __shared__ __align__(16) float Mt[64][LSTR];   // [j][oc]
  const int t = threadIdx.x;
  const int b = blockIdx.y;
  const long long n0 = (long long)blockIdx.x * 64;
  float* vb = vy + (size_t)b * 64 * NPIX;
  const float* Mb = M + (size_t)b * 4096;

  {
    const int p4 = (t & 15) * 4;
#pragma unroll
    for (int r = 0; r < 4; ++r) {
      const int j = (t >> 4) + 16 * r;
      const float4 v = *(const float4*)(vb + (size_t)j * NPIX + n0 + p4);
      *(float4*)(&vs[j][p4]) = v;
    }
    const int j4 = (t & 15) * 4;
#pragma unroll
    for (int r = 0; r < 4; ++r) {
      const int oc = (t >> 4) + 16 * r;
      const float4 m = *(const float4*)(Mb + (size_t)oc * 64 + j4);
      Mt[j4 + 0][oc] = m.x;
      Mt[j4 + 1][oc] = m.y;
      Mt[j4 + 2][oc] = m.z;
      Mt[j4 + 3][oc] = m.w;
    }
  }
  __syncthreads();

  const int ocl0 = (t >> 4) * 4;
  const int p0   = (t & 15) * 4;
  float acc[4][4] = {};
#pragma unroll 4
  for (int j = 0; j < 64; ++j) {
    const float4 a  = *(const float4*)(&Mt[j][ocl0]);
    const float4 bq = *(const float4*)(&vs[j][p0]);
    const float av[4] = {a.x, a.y, a.z, a.w};
    const float bv[4] = {bq.x, bq.y, bq.z, bq.w};
#pragma unroll
    for (int i = 0; i < 4; ++i)
#pragma unroll
      for (int p = 0; p < 4; ++p)
        acc[i][p] = fmaf(av[i], bv[p], acc[i][p]);
  }
#pragma unroll
  for (int i = 0; i < 4; ++i) {
    float4 o;
    o.x = acc[i][0]; o.y = acc[i][1]; o.z = acc[i][2]; o.w = acc[i][3];
    *(float4*)(vb + (size_t)(ocl0 + i) * NPIX + n0 + p0) = o;
  }
}

extern "C" void kernel_launch(void* const* d_in, const int* in_sizes, int n_in,
                              void* d_out, int out_size, void* d_ws, size_t ws_size,
                              hipStream_t stream) {
  const float* x     = (const float*)d_in[0];
  const float* wqkv  = (const float*)d_in[1];
  const float* wdw   = (const float*)d_in[2];
  const float* wproj = (const float*)d_in[3];
  const float* temp  = (const float*)d_in[4];
  const float* a1    = (const float*)d_in[5];
  const float* a2    = (const float*)d_in[6];
  const float* a3    = (const float*)d_in[7];
  float* y = (float*)d_out;
  float* ws = (float*)d_ws;

  const size_t ws_floats = ws_size / sizeof(float);
  const size_t smalls = SZ_GRAM + SZ_NORM + SZ_M + SZ_PART;
  const size_t needA = 4 * SZ_QKV1_1B + (size_t)B_ * SZ_QKB_1B + smalls; // ~479 MB

  dim3 blk(256);
  if (ws_floats >= needA) {
    // ---- Tier A: two half-batches of 4 through k1/k2, single batched k3 ----
    float* qkv1  = ws;                               // [4][192][N]
    float* qkb   = qkv1 + 4 * SZ_QKV1_1B;            // [8][128][N]
    float* gram  = qkb + (size_t)B_ * SZ_QKB_1B;
    float* norms = gram + SZ_GRAM;
    float* M     = norms + SZ_NORM;
    float* part  = M + SZ_M;

    for (int half = 0; half < 2; ++half) {
      const int b0 = half * 4;
      k1_qkv1x1<<<dim3(1024, 3, 4), blk, 0, stream>>>(x, wqkv, qkv1, b0);
      k2_dwconv<<<dim3(16, C3, 4), blk, 0, stream>>>(
          qkv1, wdw, qkb + (size_t)b0 * SZ_QKB_1B, SZ_QKB_1B,
          y + (size_t)b0 * 64 * NPIX);
    }
    k3_gram<<<dim3(K3_CHUNKS, 2, B_), dim3(1024), 0, stream>>>(
        qkb, SZ_QKB_1B, part, 0);
    k3_reduce<<<dim3(68), blk, 0, stream>>>(part, gram, norms);
    k4_attn<<<dim3(B_), blk, 0, stream>>>(gram, norms, temp, a1, a2, a3, wproj, M);
    k5_out<<<dim3(1024, B_), blk, 0, stream>>>(y, M);
  } else {
    // ---- Tier B fallback: per-batch loop (round-2 structure) ----
    float* qkv1  = ws;                               // [1][192][N]
    float* qkb   = qkv1 + SZ_QKV1_1B;                // [1][128][N]
    float* gram  = qkb + SZ_QKB_1B;
    float* norms = gram + SZ_GRAM;
    float* M     = norms + SZ_NORM;
    float* part  = M + SZ_M;

    for (int b = 0; b < B_; ++b) {
      k1_qkv1x1<<<dim3(1024, 3, 1), blk, 0, stream>>>(x, wqkv, qkv1, b);
      k2_dwconv<<<dim3(16, C3, 1), blk, 0, stream>>>(
          qkv1, wdw, qkb, 0, y + (size_t)b * 64 * NPIX);
      k3_gram<<<dim3(K3_CHUNKS, 2, 1), dim3(1024), 0, stream>>>(qkb, 0, part, b);
    }
    k3_reduce<<<dim3(68), blk, 0, stream>>>(part, gram, norms);
    k4_attn<<<dim3(B_), blk, 0, stream>>>(gram, norms, temp, a1, a2, a3, wproj, M);
    k5_out<<<dim3(1024, B_), blk, 0, stream>>>(y, M);
  }
}

// Round 4
// 751.554 us; speedup vs baseline: 2.6181x; 1.0137x over previous
//
#include <hip/hip_runtime.h>
#include <math.h>

// Problem constants (fixed by setup_inputs)
constexpr int B_   = 8;
constexpr int CIN  = 64;     // dim
constexpr int C3   = 192;    // 3*dim
constexpr int HWID = 256;
constexpr long long NPIX = 65536; // 256*256

// k3 partial-reduction geometry (R4: 256-px chunks, LDS-staged)
constexpr int K3_CHUNKS = 256;   // 256 pixels per chunk
constexpr int K3_CELLS  = 1088;  // 1024 gram + 32 qn + 32 kn

// Per-batch buffer sizes (floats)
constexpr size_t SZ_QKV1_1B = (size_t)C3 * NPIX;   // 12.58M  (one batch, 192ch)
constexpr size_t SZ_QKB_1B  = (size_t)128 * NPIX;  //  8.39M  (one batch, q+k)
constexpr size_t SZ_GRAM = (size_t)B_ * 2 * 32 * 32;
constexpr size_t SZ_NORM = (size_t)B_ * 2 * 64;
constexpr size_t SZ_M    = (size_t)B_ * 64 * 64;
constexpr size_t SZ_PART = (size_t)B_ * 2 * K3_CELLS * K3_CHUNKS;

// LDS tile stride for the GEMM kernels
constexpr int LSTR = 68;

// ---------------------------------------------------------------------------
// K1: qkv1 = W_qkv (192x64) @ x_b (64xN).  LDS-tiled GEMM, thread = 4x4 tile.
// grid (1024, 3 oc-tiles, nb local batches).  Writes qkv1[lb].
// ---------------------------------------------------------------------------
__global__ __launch_bounds__(256) void k1_qkv1x1(const float* __restrict__ x,
                                                 const float* __restrict__ wqkv,
                                                 float* __restrict__ qkv1, int b0) {
  __shared__ __align__(16) float xs[64][LSTR];   // [ic][pix]
  __shared__ __align__(16) float Wt[64][LSTR];   // [ic][oc]  (transposed W)
  const int t = threadIdx.x;
  const int lb = blockIdx.z;
  const long long n0 = (long long)blockIdx.x * 64;
  const int oc0 = blockIdx.y * 64;
  const float* xb = x + (size_t)(b0 + lb) * CIN * NPIX;
  float* outb = qkv1 + (size_t)lb * SZ_QKV1_1B;

  {
    const int p4 = (t & 15) * 4;
#pragma unroll
    for (int r = 0; r < 4; ++r) {
      const int ic = (t >> 4) + 16 * r;
      const float4 v = *(const float4*)(xb + (size_t)ic * NPIX + n0 + p4);
      *(float4*)(&xs[ic][p4]) = v;
    }
    const int ic4 = (t & 15) * 4;
#pragma unroll
    for (int r = 0; r < 4; ++r) {
      const int ocl = (t >> 4) + 16 * r;
      const float4 w = *(const float4*)(wqkv + (size_t)(oc0 + ocl) * 64 + ic4);
      Wt[ic4 + 0][ocl] = w.x;
      Wt[ic4 + 1][ocl] = w.y;
      Wt[ic4 + 2][ocl] = w.z;
      Wt[ic4 + 3][ocl] = w.w;
    }
  }
  __syncthreads();

  const int ocl0 = (t >> 4) * 4;
  const int p0   = (t & 15) * 4;
  float acc[4][4] = {};
#pragma unroll 4
  for (int j = 0; j < 64; ++j) {
    const float4 a  = *(const float4*)(&Wt[j][ocl0]);
    const float4 bq = *(const float4*)(&xs[j][p0]);
    const float av[4] = {a.x, a.y, a.z, a.w};
    const float bv[4] = {bq.x, bq.y, bq.z, bq.w};
#pragma unroll
    for (int i = 0; i < 4; ++i)
#pragma unroll
      for (int p = 0; p < 4; ++p)
        acc[i][p] = fmaf(av[i], bv[p], acc[i][p]);
  }
#pragma unroll
  for (int i = 0; i < 4; ++i) {
    float4 o;
    o.x = acc[i][0]; o.y = acc[i][1]; o.z = acc[i][2]; o.w = acc[i][3];
    *(float4*)(outb + (size_t)(oc0 + ocl0 + i) * NPIX + n0 + p0) = o;
  }
}

// ---------------------------------------------------------------------------
// K2: depthwise 3x3 pad 1.  16 output rows/block (stage 18 rows), rolling
// 3-row register window.  grid (16, 192, nb).
// ---------------------------------------------------------------------------
__global__ __launch_bounds__(256) void k2_dwconv(const float* __restrict__ qkv1,
                                                 const float* __restrict__ wdw,
                                                 float* __restrict__ qkb,
                                                 size_t qkb_stride,
                                                 float* __restrict__ vout) {
  const int r0 = blockIdx.x * 16;
  const int ch = blockIdx.y;
  const int lb = blockIdx.z;
  const int t  = threadIdx.x;
  __shared__ __align__(16) float sm[18][256];
  const float* p = qkv1 + (size_t)lb * SZ_QKV1_1B + (size_t)ch * NPIX;

  for (int idx = t; idx < 18 * 64; idx += 256) {
    const int rr = idx >> 6;
    const int c4 = (idx & 63) * 4;
    const int gr = r0 - 1 + rr;
    float4 v = make_float4(0.f, 0.f, 0.f, 0.f);
    if (gr >= 0 && gr < HWID) v = *(const float4*)(p + (size_t)gr * HWID + c4);
    *(float4*)(&sm[rr][c4]) = v;
  }
  float w[9];
#pragma unroll
  for (int i = 0; i < 9; ++i) w[i] = wdw[ch * 9 + i];
  __syncthreads();

  const int col = t;
  const bool cl = (col > 0), cr = (col < 255);
  float l0 = cl ? sm[0][col - 1] : 0.f, m0 = sm[0][col], r0v = cr ? sm[0][col + 1] : 0.f;
  float l1 = cl ? sm[1][col - 1] : 0.f, m1 = sm[1][col], r1v = cr ? sm[1][col + 1] : 0.f;
  float* dst = (ch < 128)
                   ? (qkb + (size_t)lb * qkb_stride + (size_t)ch * NPIX)
                   : (vout + (size_t)lb * 64 * NPIX + (size_t)(ch - 128) * NPIX);
#pragma unroll
  for (int k = 0; k < 16; ++k) {
    const float l2 = cl ? sm[k + 2][col - 1] : 0.f;
    const float m2 = sm[k + 2][col];
    const float r2v = cr ? sm[k + 2][col + 1] : 0.f;
    float acc = w[0] * l0;
    acc = fmaf(w[1], m0, acc);  acc = fmaf(w[2], r0v, acc);
    acc = fmaf(w[3], l1, acc);  acc = fmaf(w[4], m1, acc);
    acc = fmaf(w[5], r1v, acc); acc = fmaf(w[6], l2, acc);
    acc = fmaf(w[7], m2, acc);  acc = fmaf(w[8], r2v, acc);
    dst[(size_t)(r0 + k) * HWID + col] = acc;
    l0 = l1; m0 = m1; r0v = r1v;
    l1 = l2; m1 = m2; r1v = r2v;
  }
}

// ---------------------------------------------------------------------------
// K3: Gram partials.  R4 REDESIGN: LDS-staged.  Block = 256 thr owns one
// (256-px chunk, head, batch); stages q[32][256]+k[32][256] in LDS (66.5 KB,
// 2 blocks/CU) so global traffic is exactly 1x (was 8x L1/L2 amplification,
// 134M VMEM instrs -> VMEM-issue bound at 143 us).  Thread = 8x8 register
// tile fed by ds_read_b128; per wave per step 16 ds_reads (~192 cyc) vs
// 512 FMA-issue cyc -> VALU/HBM bound.  grid (256, 2, nb).
// part layout [bh][cell][chunk] for a coalesced wave-per-cell reducer.
// ---------------------------------------------------------------------------
__global__ __launch_bounds__(256) void k3_gram(const float* __restrict__ qkbuf,
                                               size_t qkb_stride,
                                               float* __restrict__ part, int b0) {
  constexpr int LS = 260;   // LDS row stride (floats), 16B-aligned rows
  __shared__ __align__(16) float qs[32][LS];
  __shared__ __align__(16) float ks[32][LS];
  const int chunk = blockIdx.x;   // 0..255, 256 pixels each
  const int h = blockIdx.y;       // 0..1
  const int lb = blockIdx.z;
  const int b = b0 + lb;
  const int t = threadIdx.x;      // 0..255
  const float* base = qkbuf + (size_t)lb * qkb_stride;
  const float* qg = base + (size_t)(h * 32) * NPIX + (size_t)chunk * 256;
  const float* kg = base + (size_t)(64 + h * 32) * NPIX + (size_t)chunk * 256;

  // stage q,k tiles: 32 rows x 256 floats each, coalesced float4
  {
    const int col4 = (t & 63) * 4;
    const int rb = t >> 6;          // 0..3
#pragma unroll
    for (int it = 0; it < 8; ++it) {
      const int row = it * 4 + rb;
      *(float4*)(&qs[row][col4]) = *(const float4*)(qg + (size_t)row * NPIX + col4);
      *(float4*)(&ks[row][col4]) = *(const float4*)(kg + (size_t)row * NPIX + col4);
    }
  }
  __syncthreads();

  const int nt = t & 15;          // n-lane within 16-group
  const int tile = t >> 4;        // 0..15
  const int c0 = (tile & 3) * 8;
  const int d0 = (tile >> 2) * 8;
  const bool do_qn = (d0 == 0);   // tiles 0..3 cover all c
  const bool do_kn = (c0 == 0);   // tiles 0,4,8,12 cover all d

  float acc[8][8] = {};
  float qn[8] = {}, kn[8] = {};
#pragma unroll 1
  for (int s = 0; s < 4; ++s) {
    const int nn = s * 64 + nt * 4;
    float4 qv[8], kv[8];
#pragma unroll
    for (int i = 0; i < 8; ++i) qv[i] = *(const float4*)(&qs[c0 + i][nn]);
#pragma unroll
    for (int j = 0; j < 8; ++j) kv[j] = *(const float4*)(&ks[d0 + j][nn]);
#pragma unroll
    for (int i = 0; i < 8; ++i)
#pragma unroll
      for (int j = 0; j < 8; ++j) {
        float a = acc[i][j];
        a = fmaf(qv[i].x, kv[j].x, a);
        a = fmaf(qv[i].y, kv[j].y, a);
        a = fmaf(qv[i].z, kv[j].z, a);
        a = fmaf(qv[i].w, kv[j].w, a);
        acc[i][j] = a;
      }
    if (do_qn) {
#pragma unroll
      for (int i = 0; i < 8; ++i) {
        float a = qn[i];
        a = fmaf(qv[i].x, qv[i].x, a);
        a = fmaf(qv[i].y, qv[i].y, a);
        a = fmaf(qv[i].z, qv[i].z, a);
        a = fmaf(qv[i].w, qv[i].w, a);
        qn[i] = a;
      }
    }
    if (do_kn) {
#pragma unroll
      for (int j = 0; j < 8; ++j) {
        float a = kn[j];
        a = fmaf(kv[j].x, kv[j].x, a);
        a = fmaf(kv[j].y, kv[j].y, a);
        a = fmaf(kv[j].z, kv[j].z, a);
        a = fmaf(kv[j].w, kv[j].w, a);
        kn[j] = a;
      }
    }
  }

  // reduce over the 16 n-lanes; part layout [bh][cell][chunk]
  float* pb = part + ((size_t)(b * 2 + h) * K3_CELLS) * K3_CHUNKS + chunk;
#pragma unroll
  for (int i = 0; i < 8; ++i)
#pragma unroll
    for (int j = 0; j < 8; ++j) {
      float v = acc[i][j];
      v += __shfl_xor(v, 1); v += __shfl_xor(v, 2);
      v += __shfl_xor(v, 4); v += __shfl_xor(v, 8);
      if (nt == 0) pb[(size_t)((c0 + i) * 32 + (d0 + j)) * K3_CHUNKS] = v;
    }
  if (do_qn) {
#pragma unroll
    for (int i = 0; i < 8; ++i) {
      float v = qn[i];
      v += __shfl_xor(v, 1); v += __shfl_xor(v, 2);
      v += __shfl_xor(v, 4); v += __shfl_xor(v, 8);
      if (nt == 0) pb[(size_t)(1024 + c0 + i) * K3_CHUNKS] = v;
    }
  }
  if (do_kn) {
#pragma unroll
    for (int j = 0; j < 8; ++j) {
      float v = kn[j];
      v += __shfl_xor(v, 1); v += __shfl_xor(v, 2);
      v += __shfl_xor(v, 4); v += __shfl_xor(v, 8);
      if (nt == 0) pb[(size_t)(1056 + d0 + j) * K3_CHUNKS] = v;
    }
  }
}

// ---------------------------------------------------------------------------
// K3R: sum chunk partials -> gram/norms.  Wave-per-cell: lane l sums chunks
// l, l+64, l+128, l+192 (coalesced), butterfly-reduce 64 lanes.
// grid (17408/4 = 4352) x 256.
// ---------------------------------------------------------------------------
__global__ __launch_bounds__(256) void k3_reduce(const float* __restrict__ part,
                                                 float* __restrict__ gram,
                                                 float* __restrict__ norms) {
  const int t = threadIdx.x;
  const int e = blockIdx.x * 4 + (t >> 6);   // cell id, 0..17407
  const int l = t & 63;
  const float* p = part + (size_t)e * K3_CHUNKS;
  float s = p[l] + p[l + 64] + p[l + 128] + p[l + 192];
  s += __shfl_xor(s, 1);  s += __shfl_xor(s, 2);
  s += __shfl_xor(s, 4);  s += __shfl_xor(s, 8);
  s += __shfl_xor(s, 16); s += __shfl_xor(s, 32);
  if (l == 0) {
    const int bh = e / K3_CELLS;
    const int cell = e - bh * K3_CELLS;
    if (cell < 1024) gram[(size_t)bh * 1024 + cell] = s;
    else             norms[(size_t)bh * 64 + (cell - 1024)] = s;
  }
}

// ---------------------------------------------------------------------------
// K4: normalize gram -> attn; rank-based top-k (16,21,24) masked softmaxes;
// fold with W_proj -> M (64x64).  (unchanged)
// ---------------------------------------------------------------------------
__global__ __launch_bounds__(256) void k4_attn(const float* __restrict__ gram,
                                               const float* __restrict__ norms,
                                               const float* __restrict__ temp,
                                               const float* __restrict__ a1,
                                               const float* __restrict__ a2,
                                               const float* __restrict__ a3,
                                               const float* __restrict__ wproj,
                                               float* __restrict__ M) {
  const int b = blockIdx.x;
  const int t = threadIdx.x;
  __shared__ float A[2][32][32];
  if (t < 64) {
    const int h = t >> 5, c = t & 31;
    const float* g = gram + (((size_t)b * 2 + h) * 32 + c) * 32;
    const float* nb = norms + ((size_t)b * 2 + h) * 64;
    const float qn = fmaxf(sqrtf(nb[c]), 1e-12f);
    const float tmph = temp[h];
    float v[32];
#pragma unroll
    for (int d = 0; d < 32; ++d) {
      const float kn = fmaxf(sqrtf(nb[32 + d]), 1e-12f);
      v[d] = g[d] / (qn * kn) * tmph;
    }
    int rank[32];
#pragma unroll
    for (int i = 0; i < 32; ++i) {
      int r = 0;
#pragma unroll
      for (int j = 0; j < 32; ++j)
        r += (v[j] > v[i]) || (v[j] == v[i] && j < i);
      rank[i] = r;
    }
    float acc[32];
#pragma unroll
    for (int d = 0; d < 32; ++d) acc[d] = 0.f;
    const float aws[3] = {a1[0], a2[0], a3[0]};
    const int kvs[3] = {16, 21, 24};  // C/2, 2C/3, 3C/4 for C=32
#pragma unroll 1
    for (int kk = 0; kk < 3; ++kk) {
      float mx = -3.4e38f;
#pragma unroll
      for (int d = 0; d < 32; ++d)
        if (rank[d] < kvs[kk]) mx = fmaxf(mx, v[d]);
      float s = 0.f;
#pragma unroll
      for (int d = 0; d < 32; ++d)
        if (rank[d] < kvs[kk]) s += expf(v[d] - mx);
      const float inv = aws[kk] / s;
#pragma unroll
      for (int d = 0; d < 32; ++d)
        if (rank[d] < kvs[kk]) acc[d] += expf(v[d] - mx) * inv;
    }
#pragma unroll
    for (int d = 0; d < 32; ++d) A[h][c][d] = acc[d];
  }
  __syncthreads();
  for (int e = t; e < 4096; e += 256) {
    const int oc = e >> 6, j = e & 63, h = j >> 5, d = j & 31;
    float s = 0.f;
#pragma unroll
    for (int c = 0; c < 32; ++c)
      s += wproj[oc * 64 + h * 32 + c] * A[h][c][d];
    M[(size_t)b * 4096 + e] = s;
  }
}

// ---------------------------------------------------------------------------
// K5: y[b] = M[b] (64x64) @ v[b] (64xN), IN PLACE on d_out.  LDS-tiled GEMM.
// grid (1024, 8).
// ---------------------------------------------------------------------------
__global__ __launch_bounds__(256) void k5_out(float* vy,
                                              const float* __restrict__ M) {
  __shared__ __align__(16) float vs[64][LSTR];   // [j][pix]
  __shared__ __align__(16) float Mt[64][LSTR];   // [j][oc]
  const int t = threadIdx.x;
  const int b = blockIdx.y;
  const long long n0 = (long long)blockIdx.x * 64;
  float* vb = vy + (size_t)b * 64 * NPIX;
  const float* Mb = M + (size_t)b * 4096;

  {
    const int p4 = (t & 15) * 4;
#pragma unroll
    for (int r = 0; r < 4; ++r) {
      const int j = (t >> 4) + 16 * r;
      const float4 v = *(const float4*)(vb + (size_t)j * NPIX + n0 + p4);
      *(float4*)(&vs[j][p4]) = v;
    }
    const int j4 = (t & 15) * 4;
#pragma unroll
    for (int r = 0; r < 4; ++r) {
      const int oc = (t >> 4) + 16 * r;
      const float4 m = *(const float4*)(Mb + (size_t)oc * 64 + j4);
      Mt[j4 + 0][oc] = m.x;
      Mt[j4 + 1][oc] = m.y;
      Mt[j4 + 2][oc] = m.z;
      Mt[j4 + 3][oc] = m.w;
    }
  }
  __syncthreads();

  const int ocl0 = (t >> 4) * 4;
  const int p0   = (t & 15) * 4;
  float acc[4][4] = {};
#pragma unroll 4
  for (int j = 0; j < 64; ++j) {
    const float4 a  = *(const float4*)(&Mt[j][ocl0]);
    const float4 bq = *(const float4*)(&vs[j][p0]);
    const float av[4] = {a.x, a.y, a.z, a.w};
    const float bv[4] = {bq.x, bq.y, bq.z, bq.w};
#pragma unroll
    for (int i = 0; i < 4; ++i)
#pragma unroll
      for (int p = 0; p < 4; ++p)
        acc[i][p] = fmaf(av[i], bv[p], acc[i][p]);
  }
#pragma unroll
  for (int i = 0; i < 4; ++i) {
    float4 o;
    o.x = acc[i][0]; o.y = acc[i][1]; o.z = acc[i][2]; o.w = acc[i][3];
    *(float4*)(vb + (size_t)(ocl0 + i) * NPIX + n0 + p0) = o;
  }
}

extern "C" void kernel_launch(void* const* d_in, const int* in_sizes, int n_in,
                              void* d_out, int out_size, void* d_ws, size_t ws_size,
                              hipStream_t stream) {
  const float* x     = (const float*)d_in[0];
  const float* wqkv  = (const float*)d_in[1];
  const float* wdw   = (const float*)d_in[2];
  const float* wproj = (const float*)d_in[3];
  const float* temp  = (const float*)d_in[4];
  const float* a1    = (const float*)d_in[5];
  const float* a2    = (const float*)d_in[6];
  const float* a3    = (const float*)d_in[7];
  float* y = (float*)d_out;
  float* ws = (float*)d_ws;

  const size_t ws_floats = ws_size / sizeof(float);
  const size_t smalls = SZ_GRAM + SZ_NORM + SZ_M + SZ_PART;
  const size_t needA = 4 * SZ_QKV1_1B + (size_t)B_ * SZ_QKB_1B + smalls; // ~488 MB

  dim3 blk(256);
  if (ws_floats >= needA) {
    // ---- Tier A: two half-batches of 4 through k1/k2, single batched k3 ----
    float* qkv1  = ws;                               // [4][192][N]
    float* qkb   = qkv1 + 4 * SZ_QKV1_1B;            // [8][128][N]
    float* gram  = qkb + (size_t)B_ * SZ_QKB_1B;
    float* norms = gram + SZ_GRAM;
    float* M     = norms + SZ_NORM;
    float* part  = M + SZ_M;

    for (int half = 0; half < 2; ++half) {
      const int b0 = half * 4;
      k1_qkv1x1<<<dim3(1024, 3, 4), blk, 0, stream>>>(x, wqkv, qkv1, b0);
      k2_dwconv<<<dim3(16, C3, 4), blk, 0, stream>>>(
          qkv1, wdw, qkb + (size_t)b0 * SZ_QKB_1B, SZ_QKB_1B,
          y + (size_t)b0 * 64 * NPIX);
    }
    k3_gram<<<dim3(K3_CHUNKS, 2, B_), blk, 0, stream>>>(
        qkb, SZ_QKB_1B, part, 0);
    k3_reduce<<<dim3(4352), blk, 0, stream>>>(part, gram, norms);
    k4_attn<<<dim3(B_), blk, 0, stream>>>(gram, norms, temp, a1, a2, a3, wproj, M);
    k5_out<<<dim3(1024, B_), blk, 0, stream>>>(y, M);
  } else {
    // ---- Tier B fallback: per-batch loop ----
    float* qkv1  = ws;                               // [1][192][N]
    float* qkb   = qkv1 + SZ_QKV1_1B;                // [1][128][N]
    float* gram  = qkb + SZ_QKB_1B;
    float* norms = gram + SZ_GRAM;
    float* M     = norms + SZ_NORM;
    float* part  = M + SZ_M;

    for (int b = 0; b < B_; ++b) {
      k1_qkv1x1<<<dim3(1024, 3, 1), blk, 0, stream>>>(x, wqkv, qkv1, b);
      k2_dwconv<<<dim3(16, C3, 1), blk, 0, stream>>>(
          qkv1, wdw, qkb, 0, y + (size_t)b * 64 * NPIX);
      k3_gram<<<dim3(K3_CHUNKS, 2, 1), blk, 0, stream>>>(qkb, 0, part, b);
    }
    k3_reduce<<<dim3(4352), blk, 0, stream>>>(part, gram, norms);
    k4_attn<<<dim3(B_), blk, 0, stream>>>(gram, norms, temp, a1, a2, a3, wproj, M);
    k5_out<<<dim3(1024, B_), blk, 0, stream>>>(y, M);
  }
}